// Round 1
// baseline (279.561 us; speedup 1.0000x reference)
//
#include <hip/hip_runtime.h>
#include <hip/hip_bf16.h>

// Problem constants (B, N, D fixed by the reference)
#define B_ 32
#define N_ 4096
#define D_ 256
#define K_ 2048            // max(1, int(N * (1 - 0.5)))
#define SORT_THREADS 1024

// ---------------------------------------------------------------------------
// Kernel 1: per-batch-row key computation + full bitonic sort (descending).
// Key = (orderable(f32 noisy) << 32) | ~index  -> descending sort gives
// descending value, ties broken by LOWER index first (matches lax.top_k).
// Also zeroes the mean accumulator for this launch.
// ---------------------------------------------------------------------------
__global__ __launch_bounds__(SORT_THREADS) void sort_kernel(
    const float* __restrict__ attn, const float* __restrict__ noise,
    int* __restrict__ sortedIdx, float* __restrict__ meanAccum) {
  __shared__ unsigned long long keys[N_];  // 32 KiB
  const int b = blockIdx.x;
  const int tid = threadIdx.x;

  // --- compute noisy scores, mirroring the reference f32 op order ---
  for (int i = tid; i < N_; i += SORT_THREADS) {
    float u = noise[b * N_ + i];
    float a = attn[b * N_ + i];
    float x = __fadd_rn(u, 1e-10f);              // u + 1e-10
    float l1 = (float)log((double)x);            // ~correctly-rounded f32 log
    float inner = __fadd_rn(-l1, 1e-10f);        // -log(u+1e-10) + 1e-10
    float g = -(float)log((double)inner);        // gumbel
    float noisy = __fadd_rn(a, __fmul_rn(0.1f, g));  // attn + 0.1*g (no FMA)
    unsigned int fb = __float_as_uint(noisy);
    fb = (fb & 0x80000000u) ? ~fb : (fb | 0x80000000u);  // orderable f32
    keys[i] = ((unsigned long long)fb << 32) | (unsigned int)(~i);
  }
  __syncthreads();

  // --- bitonic sort, descending ---
  for (int k = 2; k <= N_; k <<= 1) {
    for (int j = k >> 1; j > 0; j >>= 1) {
      for (int t = tid; t < (N_ / 2); t += SORT_THREADS) {
        int i = ((t & ~(j - 1)) << 1) | (t & (j - 1));
        int ixj = i | j;
        unsigned long long a = keys[i];
        unsigned long long c = keys[ixj];
        bool descSeg = ((i & k) == 0);
        bool doSwap = descSeg ? (a < c) : (a > c);
        if (doSwap) { keys[i] = c; keys[ixj] = a; }
      }
      __syncthreads();
    }
  }

  // --- write sorted indices; positions [0,K) = selected, [K,N) = pruned ---
  for (int i = tid; i < N_; i += SORT_THREADS) {
    sortedIdx[b * N_ + i] = (int)(~(unsigned int)(keys[i] & 0xFFFFFFFFu));
  }
  // zero the mean accumulator (ws is poisoned 0xAA each launch)
  for (int d = tid; d < D_; d += SORT_THREADS) meanAccum[b * D_ + d] = 0.0f;
}

// ---------------------------------------------------------------------------
// Kernel 2: accumulate sum of pruned rows into meanAccum[b][d].
// Grid (16 chunks, 32 batches), 256 threads. Each block: 128 pruned rows,
// float4 coalesced loads, LDS reduce over 4 row-groups, 4 atomicAdds.
// ---------------------------------------------------------------------------
__global__ __launch_bounds__(256) void mean_kernel(
    const float* __restrict__ seq, const int* __restrict__ sortedIdx,
    float* __restrict__ meanAccum) {
  const int b = blockIdx.y;
  const int chunk = blockIdx.x;           // 0..15
  const int tid = threadIdx.x;
  const int dv = tid & 63;                // float4 column 0..63
  const int sub = tid >> 6;               // row subgroup 0..3
  const int base = b * N_ + K_ + chunk * 128;

  float4 acc = make_float4(0.f, 0.f, 0.f, 0.f);
  for (int r = sub; r < 128; r += 4) {
    int idx = sortedIdx[base + r];
    const float4* row = (const float4*)(seq + ((size_t)b * N_ + idx) * D_);
    float4 v = row[dv];
    acc.x += v.x; acc.y += v.y; acc.z += v.z; acc.w += v.w;
  }

  __shared__ float4 red[4][64];
  red[sub][dv] = acc;
  __syncthreads();
  if (sub == 0) {
    float4 s0 = red[0][dv], s1 = red[1][dv], s2 = red[2][dv], s3 = red[3][dv];
    float sx = s0.x + s1.x + s2.x + s3.x;
    float sy = s0.y + s1.y + s2.y + s3.y;
    float sz = s0.z + s1.z + s2.z + s3.z;
    float sw = s0.w + s1.w + s2.w + s3.w;
    float* dst = meanAccum + b * D_ + dv * 4;
    atomicAdd(dst + 0, sx);
    atomicAdd(dst + 1, sy);
    atomicAdd(dst + 2, sz);
    atomicAdd(dst + 3, sw);
  }
}

// ---------------------------------------------------------------------------
// Kernel 3: out[b][j][d] = seq[b][top_idx[b][j]][d] + 0.05 * (sum[b][d]/2048)
// One float4 per thread; flat thread id == flat float4 output index.
// ---------------------------------------------------------------------------
__global__ __launch_bounds__(256) void out_kernel(
    const float* __restrict__ seq, const int* __restrict__ sortedIdx,
    const float* __restrict__ meanAccum, float* __restrict__ out) {
  const unsigned int t = blockIdx.x * 256u + threadIdx.x;  // < B*K*D/4 = 4194304
  const int dv = t & 63;                 // float4 column
  const int j = (t >> 6) & (K_ - 1);     // rank within top-k
  const int b = t >> 17;                 // batch

  int idx = sortedIdx[b * N_ + j];
  float4 v = ((const float4*)(seq + ((size_t)b * N_ + idx) * D_))[dv];
  float4 m = ((const float4*)(meanAccum + b * D_))[dv];
  const float inv_cnt = 1.0f / 2048.0f;  // count = 2048 (+1e-10 is sub-ulp)
  float4 o;
  o.x = v.x + 0.05f * (m.x * inv_cnt);
  o.y = v.y + 0.05f * (m.y * inv_cnt);
  o.z = v.z + 0.05f * (m.z * inv_cnt);
  o.w = v.w + 0.05f * (m.w * inv_cnt);
  ((float4*)out)[t] = o;
}

// ---------------------------------------------------------------------------
extern "C" void kernel_launch(void* const* d_in, const int* in_sizes, int n_in,
                              void* d_out, int out_size, void* d_ws, size_t ws_size,
                              hipStream_t stream) {
  const float* seq  = (const float*)d_in[0];
  const float* attn = (const float*)d_in[1];
  const float* nois = (const float*)d_in[2];
  float* out = (float*)d_out;

  int* sortedIdx   = (int*)d_ws;                                  // B*N int  = 512 KiB
  float* meanAccum = (float*)((char*)d_ws + (size_t)B_ * N_ * 4); // B*D f32  = 32 KiB

  sort_kernel<<<B_, SORT_THREADS, 0, stream>>>(attn, nois, sortedIdx, meanAccum);
  mean_kernel<<<dim3(16, B_), 256, 0, stream>>>(seq, sortedIdx, meanAccum);
  const int total4 = B_ * K_ * (D_ / 4);   // 4,194,304
  out_kernel<<<total4 / 256, 256, 0, stream>>>(seq, sortedIdx, meanAccum, out);
}